// Round 10
// baseline (270.376 us; speedup 1.0000x reference)
//
#include <hip/hip_runtime.h>
#include <hip/hip_bf16.h>

#define NA 50000
#define NP 1000000
#define FA 75
#define FP 14
#define H  50

typedef __attribute__((ext_vector_type(8))) short short8;
typedef __attribute__((ext_vector_type(4))) float f32x4;

__device__ __forceinline__ ushort f2bf(float f) {
    union { float f; unsigned u; } v; v.f = f;
    unsigned r = v.u + 0x7FFF + ((v.u >> 16) & 1);   // RNE
    return (ushort)(r >> 16);
}
__device__ __forceinline__ unsigned cvtpk(float lo, float hi) {
    unsigned r;
    asm("v_cvt_pk_bf16_f32 %0, %1, %2" : "=v"(r) : "v"(lo), "v"(hi));
    return r;
}
__device__ __forceinline__ ushort f2bf1(float f) { return (ushort)cvtpk(f, f); }
__device__ __forceinline__ unsigned pk_fp8(float u, float v) {
    unsigned r;
    asm("v_cvt_pk_fp8_f32 %0, %1, %2" : "=v"(r) : "v"(u), "v"(v));
    return r;
}
__device__ __forceinline__ float2 unpk_fp8(unsigned w) {
    float2 r;
    asm("v_cvt_pk_f32_fp8 %0, %1" : "=v"(r) : "v"(w));
    return r;
}
__device__ __forceinline__ short8 mk8(unsigned a, unsigned b, unsigned c, unsigned d) {
    union { unsigned u[4]; short8 s; } x; x.u[0]=a; x.u[1]=b; x.u[2]=c; x.u[3]=d; return x.s;
}
__device__ __forceinline__ float asf(unsigned u) {
    union { unsigned u; float f; } v; v.u = u; return v.f;
}

// ---------------------------------------------------------------------------
// K0: pack weights into MFMA B-fragment order (bf16), biases folded in.
// B-frag 16x16x32: lane l, elem j -> W[k = tk*32+(l>>4)*8+j][col = tn*16+(l&15)]
// WPf/WAf: [tk=4][tn=4][64][8]  K=128: k<100 weights, k==100 bias, else 0
// W2f:     [tn=8][64][8]        K=32:  k<14 weights,  k==14 bias,  else 0
// WPREf:   [tk=3][tn=12][64][8] K=96 pad from 75; N=192 [AA|U|V]
// ---------------------------------------------------------------------------
__global__ __launch_bounds__(256) void k_prep_frags(
    const float* __restrict__ W_P, const float* __restrict__ W_A,
    const float* __restrict__ W_PP, const float* __restrict__ W_PA,
    const float* __restrict__ W_AA, const float* __restrict__ W_AP,
    const float* __restrict__ b_PP, const float* __restrict__ b_PA,
    const float* __restrict__ b_P, const float* __restrict__ b_A,
    ushort* __restrict__ WPf, ushort* __restrict__ WAf, ushort* __restrict__ W2f,
    ushort* __restrict__ WPREf)
{
    const int t0 = blockIdx.x * 256 + threadIdx.x;
    const int STR = 16 * 256;
    for (int idx = t0; idx < 4*4*64*8; idx += STR) {
        int j = idx & 7, l = (idx >> 3) & 63, tn = (idx >> 9) & 3, tk = idx >> 11;
        int k = tk*32 + (l>>4)*8 + j;
        int c = tn*16 + (l&15);
        ushort vp = 0, va = 0;
        if (c < 50) {
            if (k < 100)       { vp = f2bf(W_P[k*50+c]); va = f2bf(W_A[k*50+c]); }
            else if (k == 100) { vp = f2bf(b_P[c]);      va = f2bf(b_A[c]); }
        }
        WPf[idx] = vp; WAf[idx] = va;
    }
    for (int idx = t0; idx < 8*64*8; idx += STR) {
        int j = idx & 7, l = (idx >> 3) & 63, tn = idx >> 9;
        int k = (l>>4)*8 + j;
        int c = (tn&3)*16 + (l&15);
        ushort v = 0;
        if (c < 50) {
            if (k < 14)       v = f2bf(tn < 4 ? W_PP[k*50+c] : W_PA[k*50+c]);
            else if (k == 14) v = f2bf(tn < 4 ? b_PP[c] : b_PA[c]);
        }
        W2f[idx] = v;
    }
    for (int idx = t0; idx < 3*12*64*8; idx += STR) {
        int j = idx & 7, l = (idx >> 3) & 63;
        int g = idx >> 9;
        int tn = g % 12, tk = g / 12;
        int k = tk*32 + (l>>4)*8 + j;
        int sn = tn*16 + (l&15);
        int which = sn >> 6, col = sn & 63;
        ushort v = 0;
        if (k < FA && col < H) {
            float wv = (which == 0) ? W_AA[k*H+col]
                     : (which == 1) ? W_AP[k*H+col]
                                    : W_AP[(FA+k)*H+col];
            v = f2bf(wv);
        }
        WPREf[idx] = v;
    }
}

// ---------------------------------------------------------------------------
// K1: per-atom precompute via MFMA, 64 atoms/block.
//   AAb bf16 [NA][50];  UV8[atom][64] ushort: byte0=fp8(U), byte1=fp8(V).
// ---------------------------------------------------------------------------
__global__ __launch_bounds__(256) void k_atom_pre(
    const float* __restrict__ af, const ushort* __restrict__ WPREf,
    const float* __restrict__ b_AA,
    ushort* __restrict__ AAb, ushort* __restrict__ UV8)
{
    __shared__ __align__(16) ushort sAF[64][104];
    const int t = threadIdx.x, lane = t & 63, w = t >> 6;
    const int a0 = blockIdx.x * 64, row0 = w * 16;

    for (int idx = t; idx < 64*96; idx += 256) {
        int r = idx / 96, c = idx % 96;
        int ag = a0 + r;
        float v = (c < FA && ag < NA) ? af[(size_t)ag*FA + c] : 0.f;
        sAF[r][c] = f2bf(v);
    }
    __syncthreads();

    short8 afr[3];
    #pragma unroll
    for (int tk = 0; tk < 3; ++tk)
        afr[tk] = *(const short8*)&sAF[row0 + (lane&15)][tk*32 + (lane>>4)*8];

    const short8* B = (const short8*)WPREf;
    f32x4 acc[12];
    #pragma unroll
    for (int tn = 0; tn < 12; ++tn) acc[tn] = (f32x4){0.f, 0.f, 0.f, 0.f};
    #pragma unroll
    for (int tk = 0; tk < 3; ++tk) {
        #pragma unroll
        for (int tn = 0; tn < 12; ++tn) {
            short8 b = B[(tk*12 + tn)*64 + lane];
            acc[tn] = __builtin_amdgcn_mfma_f32_16x16x32_bf16(afr[tk], b, acc[tn], 0, 0, 0);
        }
    }

    #pragma unroll
    for (int tn = 0; tn < 4; ++tn) {
        int col = tn*16 + (lane&15);
        if (col < H) {
            float ba = b_AA[col];
            #pragma unroll
            for (int reg = 0; reg < 4; ++reg) {
                int atom = a0 + row0 + (lane>>4)*4 + reg;
                if (atom < NA) {
                    AAb[(size_t)atom*H + col] = f2bf(fmaxf(acc[tn][reg] + ba, 0.f));
                    UV8[(size_t)atom*64 + col] =
                        (ushort)pk_fp8(acc[4 + tn][reg], acc[8 + tn][reg]);
                }
            }
        }
    }
}

// ---------------------------------------------------------------------------
// K2: 32 pairs/WAVE (2 strips of 16), block = 128 thr = 2 waves, grid 15625.
//   ALL vector loads via inline asm with counted vmcnt (no compiler drains):
//   weights VGPR-resident; paired UV gather (1 load/pair) + ds_bpermute;
//   biases folded into MFMA; segsum via per-lane run-walk (no shfl).
// ---------------------------------------------------------------------------
__global__ __launch_bounds__(128) void k_pairs(
    const float* __restrict__ pf, const int* __restrict__ seg, const int* __restrict__ a2p,
    const ushort* __restrict__ UV8, const float* __restrict__ b_AP,
    const ushort* __restrict__ WPf, const ushort* __restrict__ W2f,
    float* __restrict__ PAsum, float* __restrict__ Pout)
{
    __shared__ __align__(16) ushort sX[32][136];
    const int t = threadIdx.x, w = t >> 6, lane = t & 63;
    const int q = lane >> 4, m = lane & 15;
    const int row0 = w * 16;
    const int pb_u = __builtin_amdgcn_readfirstlane(blockIdx.x * 64 + w * 32);

    // scalar index loads for all 32 pairs
    const int* a2ps = a2p + 2 * pb_u;
    int pi[32], pj[32];
    #pragma unroll
    for (int i = 0; i < 32; ++i) { pi[i] = a2ps[2*i]; pj[i] = a2ps[2*i+1]; }

    // ---------------- asm load burst (order defines vmcnt counts) ----------
    unsigned bap_u;
    { unsigned voff = (unsigned)((lane < 50 ? lane : 49) << 2);
      asm volatile("global_load_dword %0, %1, %2" : "=v"(bap_u) : "v"(voff), "s"(b_AP)); }
    short8 wf2[8];
    #pragma unroll
    for (int i = 0; i < 8; ++i) {
        unsigned voff = (unsigned)((i*64 + lane) * 16);
        asm volatile("global_load_dwordx4 %0, %1, %2" : "=v"(wf2[i]) : "v"(voff), "s"(W2f));
    }
    short8 wfP[16];
    #pragma unroll
    for (int i = 0; i < 16; ++i) {
        unsigned voff = (unsigned)((i*64 + lane) * 16);
        asm volatile("global_load_dwordx4 %0, %1, %2" : "=v"(wfP[i]) : "v"(voff), "s"(WPf));
    }
    const bool isJ = (lane >= 32);
    const unsigned dsel = (unsigned)((lane & 31) << 2);
    unsigned uv0[16], uv1[16];
    #pragma unroll
    for (int i = 0; i < 16; ++i) {               // strip0: lanes 0-31 row i, 32-63 row j
        int row = isJ ? pj[i] : pi[i];
        unsigned voff = ((unsigned)row << 7) | dsel;
        asm volatile("global_load_dword %0, %1, %2" : "=v"(uv0[i]) : "v"(voff), "s"(UV8));
    }
    f32x4 pfA0, pfB0;
    { unsigned rb = (unsigned)(pb_u + m) * 56u;
      unsigned va = rb + (q == 1 ? 32u : 0u);
      unsigned vb = rb + (q == 1 ? 40u : 16u);
      asm volatile("global_load_dwordx4 %0, %1, %2" : "=v"(pfA0) : "v"(va), "s"(pf));
      asm volatile("global_load_dwordx4 %0, %1, %2" : "=v"(pfB0) : "v"(vb), "s"(pf));
    }
    #pragma unroll
    for (int i = 0; i < 16; ++i) {               // strip1
        int row = isJ ? pj[16+i] : pi[16+i];
        unsigned voff = ((unsigned)row << 7) | dsel;
        asm volatile("global_load_dword %0, %1, %2" : "=v"(uv1[i]) : "v"(voff), "s"(UV8));
    }
    f32x4 pfA1, pfB1;
    { unsigned rb = (unsigned)(pb_u + 16 + m) * 56u;
      unsigned va = rb + (q == 1 ? 32u : 0u);
      unsigned vb = rb + (q == 1 ? 40u : 16u);
      asm volatile("global_load_dwordx4 %0, %1, %2" : "=v"(pfA1) : "v"(va), "s"(pf));
      asm volatile("global_load_dwordx4 %0, %1, %2" : "=v"(pfB1) : "v"(vb), "s"(pf));
    }
    // outstanding now: 61.  strip1 group = uv1(16)+pf1(2) = 18.

    // zero-pad cols 100..127 of own rows; col100 = bf16(1.0) (P bias row)
    if (lane < 16) {
        unsigned long long* rowp = (unsigned long long*)&sX[row0 + lane][100];
        rowp[0] = 0x0000000000003F80ull;
        #pragma unroll
        for (int d = 1; d < 7; ++d) rowp[d] = 0ull;
    }

    const int addrA = (lane >> 1) << 2;          // bpermute byte addr: src lane c>>1
    const int addrB = addrA + 128;               // +32 lanes (row j half)

    auto STRIP = [&](const unsigned (&uvp)[16], const f32x4& pfA, const f32x4& pfB,
                     int sbase_u) {
        // ---- A-fragment for PP/PA GEMM (k=14 slot = 1.0 -> bias row) ----
        unsigned w0 = cvtpk(pfA.x, pfA.y);
        unsigned w1 = cvtpk(pfA.z, pfA.w);
        unsigned w2 = (q == 1) ? cvtpk(pfB.z, pfB.w) : cvtpk(pfB.x, pfB.y);
        unsigned w3 = (q == 0) ? cvtpk(pfB.z, pfB.w) : ((q == 1) ? 0x00003F80u : 0u);
        if (q >= 2) { w0 = 0; w1 = 0; w2 = 0; }
        short8 afrag = mk8(w0, w1, w2, w3);
        float bapf = asf(bap_u);

        // ---- APs via bpermute redistribution -> sX[:,0:50] ----
        #pragma unroll
        for (int it = 0; it < 16; ++it) {
            unsigned va = (unsigned)__builtin_amdgcn_ds_bpermute(addrA, (int)uvp[it]);
            unsigned vb = (unsigned)__builtin_amdgcn_ds_bpermute(addrB, (int)uvp[it]);
            unsigned sh = (unsigned)((lane & 1) << 4);
            float2 fi = unpk_fp8(va >> sh);      // (U_i, V_i) of col=lane
            float2 fj = unpk_fp8(vb >> sh);      // (U_j, V_j)
            float aps = fmaxf(fi.x + fj.y + bapf, 0.f) + fmaxf(fj.x + fi.y + bapf, 0.f);
            if (lane < H) sX[row0 + it][lane] = f2bf1(aps);
        }

        // ---- PP -> sX[:,50:100], PA -> regs (bias already in k=14 row) ----
        float pa[4][4];
        #pragma unroll
        for (int tn = 0; tn < 8; ++tn) {
            f32x4 c = {0.f, 0.f, 0.f, 0.f};
            c = __builtin_amdgcn_mfma_f32_16x16x32_bf16(afrag, wf2[tn], c, 0, 0, 0);
            int col = (tn&3)*16 + m;
            if (tn < 4) {
                if (col < H) {
                    #pragma unroll
                    for (int reg = 0; reg < 4; ++reg)
                        sX[row0 + q*4 + reg][H + col] = f2bf1(fmaxf(c[reg], 0.f));
                }
            } else {
                #pragma unroll
                for (int reg = 0; reg < 4; ++reg)
                    pa[tn-4][reg] = fmaxf(c[reg], 0.f);
            }
        }

        // ---- per-lane 4-row run-walk segsum (seg sorted) ----
        const int* sgp = seg + sbase_u;
        int sg[16];
        #pragma unroll
        for (int i = 0; i < 16; ++i) sg[i] = sgp[i];
        int s0 = q==0 ? sg[0] : q==1 ? sg[4] : q==2 ? sg[8]  : sg[12];
        int s1 = q==0 ? sg[1] : q==1 ? sg[5] : q==2 ? sg[9]  : sg[13];
        int s2 = q==0 ? sg[2] : q==1 ? sg[6] : q==2 ? sg[10] : sg[14];
        int s3 = q==0 ? sg[3] : q==1 ? sg[7] : q==2 ? sg[11] : sg[15];
        #pragma unroll
        for (int tn4 = 0; tn4 < 4; ++tn4) {
            int col = tn4*16 + m;
            bool act = col < H;
            float acc = pa[tn4][0]; int cur = s0;
            if (s1 != cur) { if (act) atomicAdd(&PAsum[(size_t)cur*H + col], acc); acc = 0.f; cur = s1; }
            acc += pa[tn4][1];
            if (s2 != cur) { if (act) atomicAdd(&PAsum[(size_t)cur*H + col], acc); acc = 0.f; cur = s2; }
            acc += pa[tn4][2];
            if (s3 != cur) { if (act) atomicAdd(&PAsum[(size_t)cur*H + col], acc); acc = 0.f; cur = s3; }
            acc += pa[tn4][3];
            if (act) atomicAdd(&PAsum[(size_t)cur*H + col], acc);
        }

        // wave-local LDS writes must land before fragment reads
        asm volatile("s_waitcnt lgkmcnt(0)" ::: "memory");
        __builtin_amdgcn_sched_barrier(0);

        // ---- P = relu(X @ WPf) (bias via col100), M=16 N=64 K=128 ----
        short8 afr[4];
        #pragma unroll
        for (int tk = 0; tk < 4; ++tk)
            afr[tk] = *(const short8*)&sX[row0 + m][tk*32 + q*8];
        f32x4 acc4[4];
        #pragma unroll
        for (int tn = 0; tn < 4; ++tn) acc4[tn] = (f32x4){0.f, 0.f, 0.f, 0.f};
        #pragma unroll
        for (int tk = 0; tk < 4; ++tk) {
            #pragma unroll
            for (int tn = 0; tn < 4; ++tn)
                acc4[tn] = __builtin_amdgcn_mfma_f32_16x16x32_bf16(afr[tk], wfP[tk*4+tn], acc4[tn], 0, 0, 0);
        }
        #pragma unroll
        for (int tn = 0; tn < 4; ++tn) {
            int col = tn*16 + m;
            if (col < H) {
                #pragma unroll
                for (int reg = 0; reg < 4; ++reg) {
                    int prow = sbase_u + q*4 + reg;
                    Pout[(size_t)prow*H + col] = fmaxf(acc4[tn][reg], 0.f);
                }
            }
        }
    };

    // strip0: wait until only strip1's 18 loads outstanding
    asm volatile("s_waitcnt vmcnt(18)" ::: "memory");
    __builtin_amdgcn_sched_barrier(0);
    STRIP(uv0, pfA0, pfB0, pb_u);

    // strip1: full drain; WAR fence on sX reuse
    asm volatile("s_waitcnt vmcnt(0)" ::: "memory");
    __builtin_amdgcn_sched_barrier(0);
    asm volatile("s_waitcnt lgkmcnt(0)" ::: "memory");
    __builtin_amdgcn_sched_barrier(0);
    STRIP(uv1, pfA1, pfB1, pb_u + 16);
}

// ---------------------------------------------------------------------------
// K3: A = relu([AAb | PAsum] @ WAf) (bias via col100), 64 atoms/block.
// ---------------------------------------------------------------------------
__global__ __launch_bounds__(256) void k_A(
    const ushort* __restrict__ AAb, const float* __restrict__ PAsum,
    const ushort* __restrict__ WAf, float* __restrict__ Aout)
{
    __shared__ __align__(16) ushort sX[64][136];
    const int t = threadIdx.x, lane = t & 63, w = t >> 6;
    const int a0 = blockIdx.x * 64;
    const int row0 = w * 16;

    for (int idx = t; idx < 64*50; idx += 256) {
        int r = idx / 50, c = idx % 50;
        int rg = a0 + r;
        ushort aa = 0; float ps = 0.f;
        if (rg < NA) { aa = AAb[(size_t)rg*H + c]; ps = PAsum[(size_t)rg*H + c]; }
        sX[r][c] = aa;
        sX[r][H + c] = f2bf1(ps);
    }
    for (int idx = t; idx < 64*28; idx += 256) {
        int r = idx / 28, c = 100 + idx % 28;
        sX[r][c] = (c == 100) ? (ushort)0x3F80 : (ushort)0;   // bias row
    }
    __syncthreads();

    short8 afr[4];
    #pragma unroll
    for (int tk = 0; tk < 4; ++tk)
        afr[tk] = *(const short8*)&sX[row0 + (lane&15)][tk*32 + (lane>>4)*8];
    const short8* B = (const short8*)WAf;
    f32x4 acc[4];
    #pragma unroll
    for (int tn = 0; tn < 4; ++tn) acc[tn] = (f32x4){0.f, 0.f, 0.f, 0.f};
    #pragma unroll
    for (int tk = 0; tk < 4; ++tk) {
        #pragma unroll
        for (int tn = 0; tn < 4; ++tn) {
            short8 b = B[(tk*4 + tn)*64 + lane];
            acc[tn] = __builtin_amdgcn_mfma_f32_16x16x32_bf16(afr[tk], b, acc[tn], 0, 0, 0);
        }
    }
    #pragma unroll
    for (int tn = 0; tn < 4; ++tn) {
        int col = tn*16 + (lane&15);
        if (col < H) {
            #pragma unroll
            for (int reg = 0; reg < 4; ++reg) {
                int row = row0 + (lane>>4)*4 + reg;
                int rg = a0 + row;
                if (rg < NA) Aout[(size_t)rg*H + col] = fmaxf(acc[tn][reg], 0.f);
            }
        }
    }
}

// ---------------------------------------------------------------------------
extern "C" void kernel_launch(void* const* d_in, const int* in_sizes, int n_in,
                              void* d_out, int out_size, void* d_ws, size_t ws_size,
                              hipStream_t stream)
{
    const float* af   = (const float*)d_in[0];
    const float* pf   = (const float*)d_in[1];
    const int*   seg  = (const int*)d_in[2];
    const int*   a2p  = (const int*)d_in[3];
    const float* W_AA = (const float*)d_in[4];
    const float* b_AA = (const float*)d_in[5];
    const float* W_PA = (const float*)d_in[6];
    const float* b_PA = (const float*)d_in[7];
    const float* W_A  = (const float*)d_in[8];
    const float* b_A  = (const float*)d_in[9];
    const float* W_AP = (const float*)d_in[10];
    const float* b_AP = (const float*)d_in[11];
    const float* W_PP = (const float*)d_in[12];
    const float* b_PP = (const float*)d_in[13];
    const float* W_P  = (const float*)d_in[14];
    const float* b_P  = (const float*)d_in[15];

    float* Aout = (float*)d_out;
    float* Pout = (float*)d_out + (size_t)NA * H;

    ushort*   AAb   = (ushort*)d_ws;                         // 5 MB
    float*    PAsum = (float*)(AAb + (size_t)NA * H);        // 10 MB
    ushort*   UV8   = (ushort*)(PAsum + (size_t)NA * H);     // 6.4 MB
    ushort*   WPf   = UV8 + (size_t)NA * 64;                 // 16 KB
    ushort*   WAf   = WPf + 4*4*64*8;                        // 16 KB
    ushort*   W2f   = WAf + 4*4*64*8;                        // 8 KB
    ushort*   WPREf = W2f + 8*64*8;                          // 36 KB

    hipMemsetAsync(PAsum, 0, (size_t)NA * H * sizeof(float), stream);
    k_prep_frags<<<16, 256, 0, stream>>>(W_P, W_A, W_PP, W_PA, W_AA, W_AP,
                                         b_PP, b_PA, b_P, b_A,
                                         WPf, WAf, W2f, WPREf);
    k_atom_pre<<<(NA + 63) / 64, 256, 0, stream>>>(af, WPREf, b_AA, AAb, UV8);
    k_pairs<<<NP / 64, 128, 0, stream>>>(pf, seg, a2p, UV8, b_AP,
                                         WPf, W2f, PAsum, Pout);
    k_A<<<(NA + 63) / 64, 256, 0, stream>>>(AAb, PAsum, WAf, Aout);
}

// Round 11
// 230.832 us; speedup vs baseline: 1.1713x; 1.1713x over previous
//
#include <hip/hip_runtime.h>
#include <hip/hip_bf16.h>

#define NA 50000
#define NP 1000000
#define FA 75
#define FP 14
#define H  50

typedef __attribute__((ext_vector_type(8))) short short8;
typedef __attribute__((ext_vector_type(4))) float f32x4;

__device__ __forceinline__ ushort f2bf(float f) {
    union { float f; unsigned u; } v; v.f = f;
    unsigned r = v.u + 0x7FFF + ((v.u >> 16) & 1);   // RNE
    return (ushort)(r >> 16);
}
__device__ __forceinline__ unsigned cvtpk(float lo, float hi) {
    unsigned r;
    asm("v_cvt_pk_bf16_f32 %0, %1, %2" : "=v"(r) : "v"(lo), "v"(hi));
    return r;
}
__device__ __forceinline__ ushort f2bf1(float f) { return (ushort)cvtpk(f, f); }
__device__ __forceinline__ unsigned pk_fp8(float u, float v) {
    unsigned r;
    asm("v_cvt_pk_fp8_f32 %0, %1, %2" : "=v"(r) : "v"(u), "v"(v));
    return r;
}
__device__ __forceinline__ float2 unpk_fp8(unsigned w) {
    float2 r;
    asm("v_cvt_pk_f32_fp8 %0, %1" : "=v"(r) : "v"(w));
    return r;
}
__device__ __forceinline__ short8 mk8(unsigned a, unsigned b, unsigned c, unsigned d) {
    union { unsigned u[4]; short8 s; } x; x.u[0]=a; x.u[1]=b; x.u[2]=c; x.u[3]=d; return x.s;
}

// ---------------------------------------------------------------------------
// K0: pack weights into MFMA B-fragment order (bf16), zero-padded.
// B-frag 16x16x32: lane l, elem j -> W[k = tk*32+(l>>4)*8+j][col = tn*16+(l&15)]
// WPf/WAf:  [tk=4][tn=4][64][8]   (K=128 pad from 100, N=64 pad from 50)
// W2f:      [tn=8][64][8]         (K=32 pad from 14; tn 0..3 = W_PP, 4..7 = W_PA)
// WPREf:    [tk=3][tn=12][64][8]  (K=96 pad from 75; N=192: [AA|pad][U|pad][V|pad])
// ---------------------------------------------------------------------------
__global__ __launch_bounds__(256) void k_prep_frags(
    const float* __restrict__ W_P, const float* __restrict__ W_A,
    const float* __restrict__ W_PP, const float* __restrict__ W_PA,
    const float* __restrict__ W_AA, const float* __restrict__ W_AP,
    ushort* __restrict__ WPf, ushort* __restrict__ WAf, ushort* __restrict__ W2f,
    ushort* __restrict__ WPREf)
{
    const int t0 = blockIdx.x * 256 + threadIdx.x;
    const int STR = 16 * 256;
    for (int idx = t0; idx < 4*4*64*8; idx += STR) {
        int j = idx & 7, l = (idx >> 3) & 63, tn = (idx >> 9) & 3, tk = idx >> 11;
        int k = tk*32 + (l>>4)*8 + j;
        int c = tn*16 + (l&15);
        ushort vp = 0, va = 0;
        if (k < 100 && c < 50) { vp = f2bf(W_P[k*50+c]); va = f2bf(W_A[k*50+c]); }
        WPf[idx] = vp; WAf[idx] = va;
    }
    for (int idx = t0; idx < 8*64*8; idx += STR) {
        int j = idx & 7, l = (idx >> 3) & 63, tn = idx >> 9;
        int k = (l>>4)*8 + j;
        int c = (tn&3)*16 + (l&15);
        ushort v = 0;
        if (k < 14 && c < 50) v = f2bf(tn < 4 ? W_PP[k*50+c] : W_PA[k*50+c]);
        W2f[idx] = v;
    }
    for (int idx = t0; idx < 3*12*64*8; idx += STR) {
        int j = idx & 7, l = (idx >> 3) & 63;
        int g = idx >> 9;            // tk*12+tn
        int tn = g % 12, tk = g / 12;
        int k = tk*32 + (l>>4)*8 + j;
        int sn = tn*16 + (l&15);
        int which = sn >> 6, col = sn & 63;
        ushort v = 0;
        if (k < FA && col < H) {
            float w = (which == 0) ? W_AA[k*H+col]
                    : (which == 1) ? W_AP[k*H+col]
                                   : W_AP[(FA+k)*H+col];
            v = f2bf(w);
        }
        WPREf[idx] = v;
    }
}

// ---------------------------------------------------------------------------
// K1: per-atom precompute via MFMA, 64 atoms/block.
//   AAb bf16 [NA][50];  UV8[atom][64] ushort: byte0=fp8(U), byte1=fp8(V).
// ---------------------------------------------------------------------------
__global__ __launch_bounds__(256) void k_atom_pre(
    const float* __restrict__ af, const ushort* __restrict__ WPREf,
    const float* __restrict__ b_AA,
    ushort* __restrict__ AAb, ushort* __restrict__ UV8)
{
    __shared__ __align__(16) ushort sAF[64][104];
    const int t = threadIdx.x, lane = t & 63, w = t >> 6;
    const int a0 = blockIdx.x * 64, row0 = w * 16;

    for (int idx = t; idx < 64*96; idx += 256) {
        int r = idx / 96, c = idx % 96;
        int ag = a0 + r;
        float v = (c < FA && ag < NA) ? af[(size_t)ag*FA + c] : 0.f;
        sAF[r][c] = f2bf(v);
    }
    __syncthreads();

    short8 afr[3];
    #pragma unroll
    for (int tk = 0; tk < 3; ++tk)
        afr[tk] = *(const short8*)&sAF[row0 + (lane&15)][tk*32 + (lane>>4)*8];

    const short8* B = (const short8*)WPREf;
    f32x4 acc[12];
    #pragma unroll
    for (int tn = 0; tn < 12; ++tn) acc[tn] = (f32x4){0.f, 0.f, 0.f, 0.f};
    #pragma unroll
    for (int tk = 0; tk < 3; ++tk) {
        #pragma unroll
        for (int tn = 0; tn < 12; ++tn) {
            short8 b = B[(tk*12 + tn)*64 + lane];
            acc[tn] = __builtin_amdgcn_mfma_f32_16x16x32_bf16(afr[tk], b, acc[tn], 0, 0, 0);
        }
    }

    #pragma unroll
    for (int tn = 0; tn < 4; ++tn) {
        int col = tn*16 + (lane&15);
        if (col < H) {
            float ba = b_AA[col];
            #pragma unroll
            for (int reg = 0; reg < 4; ++reg) {
                int atom = a0 + row0 + (lane>>4)*4 + reg;
                if (atom < NA) {
                    AAb[(size_t)atom*H + col] = f2bf(fmaxf(acc[tn][reg] + ba, 0.f));
                    UV8[(size_t)atom*64 + col] =
                        (ushort)pk_fp8(acc[4 + tn][reg], acc[8 + tn][reg]);
                }
            }
        }
    }
}

// ---------------------------------------------------------------------------
// K2: 64 pairs/block, 4 waves (r9 structure) + WEIGHT FRAGMENTS IN LDS.
//   Block staging: WPf(16KB)+W2f(8KB) -> LDS once, one __syncthreads.
//   fp8 UV8 gather burst (inline asm, one vmcnt wait); PP/PA via K=32 MFMA
//   with B from LDS; PA in regs -> wave segsum; P via 16 MFMA/wave, B from LDS.
// ---------------------------------------------------------------------------
__global__ __launch_bounds__(256) void k_pairs(
    const float* __restrict__ pf, const int* __restrict__ seg, const int* __restrict__ a2p,
    const ushort* __restrict__ UV8,
    const float* __restrict__ b_PP, const float* __restrict__ b_PA,
    const float* __restrict__ b_AP, const float* __restrict__ b_P,
    const ushort* __restrict__ WPf, const ushort* __restrict__ W2f,
    float* __restrict__ PAsum, float* __restrict__ Pout)
{
    __shared__ __align__(16) ushort sX[64][136];   // 17408 B
    __shared__ __align__(16) short8 sWP[1024];     // 16384 B: [tk*4+tn][64]
    __shared__ __align__(16) short8 sW2[512];      //  8192 B: [tn][64]

    const int t = threadIdx.x;
    const int w = t >> 6, lane = t & 63;
    const int q = lane >> 4, m = lane & 15;
    const int p0 = blockIdx.x * 64;
    const int row0 = w * 16;
    const int p0w_u = __builtin_amdgcn_readfirstlane(p0 + row0);  // uniform

    // ---- scalar loads: pair indices + segment ids for this wave's 16 pairs ----
    const int* a2ps = a2p + 2 * p0w_u;
    const int* segs = seg + p0w_u;
    int pi[16], pj[16], sg[16];
    #pragma unroll
    for (int it = 0; it < 16; ++it) {
        pi[it] = a2ps[2*it];
        pj[it] = a2ps[2*it + 1];
        sg[it] = segs[it];
    }

    // ---- stage weight fragments into LDS (24KB, cooperative) ----
    {
        const short8* gWP = (const short8*)WPf;
        #pragma unroll
        for (int i = 0; i < 4; ++i) sWP[i*256 + t] = gWP[i*256 + t];
        const short8* gW2 = (const short8*)W2f;
        #pragma unroll
        for (int i = 0; i < 2; ++i) sW2[i*256 + t] = gW2[i*256 + t];
    }
    __syncthreads();   // staging visible to all waves (also drains its vmcnt)

    // ---- pf A-frag: k = q*8+j, only q<2 carries data (k<14); convert now ----
    const float2* pf2 = (const float2*)(pf + (size_t)(p0w_u + m) * FP);
    float2 g0 = {0.f,0.f}, g1 = {0.f,0.f}, g2 = {0.f,0.f}, g3 = {0.f,0.f};
    if (q == 0)      { g0 = pf2[0]; g1 = pf2[1]; g2 = pf2[2]; g3 = pf2[3]; }  // k0..7
    else if (q == 1) { g0 = pf2[4]; g1 = pf2[5]; g2 = pf2[6]; }               // k8..13
    short8 afrag = mk8(cvtpk(g0.x, g0.y), cvtpk(g1.x, g1.y),
                       cvtpk(g2.x, g2.y), cvtpk(g3.x, g3.y));

    // ---- UV8 gather burst: 32 volatile ushort loads, one vmcnt wait ----
    unsigned uvi[16], uvj[16];
    const unsigned lo2 = (unsigned)(lane << 1);
    #pragma unroll
    for (int it = 0; it < 16; ++it) {
        unsigned offi = ((unsigned)pi[it] << 7) | lo2;
        unsigned offj = ((unsigned)pj[it] << 7) | lo2;
        asm volatile("global_load_ushort %0, %1, %2"
                     : "=v"(uvi[it]) : "v"(offi), "s"(UV8));
        asm volatile("global_load_ushort %0, %1, %2"
                     : "=v"(uvj[it]) : "v"(offj), "s"(UV8));
    }

    // zero X K-pad cols 100..127 of own rows (overlaps with loads in flight)
    if (lane < 16) {
        unsigned long long* rowp = (unsigned long long*)&sX[row0 + lane][100];
        #pragma unroll
        for (int d = 0; d < 7; ++d) rowp[d] = 0ull;
    }
    float bap = (lane < H) ? b_AP[lane] : 0.f;

    // single round-trip wait; fence so no consumer is hoisted above (rule #18)
    asm volatile("s_waitcnt vmcnt(0)" ::: "memory");
    __builtin_amdgcn_sched_barrier(0);

    // ---- APs = relu(U_i+V_j+b) + relu(U_j+V_i+b) -> sX[:,0:50] ----
    #pragma unroll
    for (int it = 0; it < 16; ++it) {
        if (lane < H) {
            float2 fi = unpk_fp8(uvi[it]);   // x=U_i, y=V_i
            float2 fj = unpk_fp8(uvj[it]);   // x=U_j, y=V_j
            float aps = fmaxf(fi.x + fj.y + bap, 0.f) + fmaxf(fj.x + fi.y + bap, 0.f);
            sX[row0 + it][lane] = f2bf1(aps);
        }
    }

    // ---- PP -> sX[:,50:100] (bf16), PA -> regs; B-frags from LDS ----
    float pa[4][4];
    {
        #pragma unroll
        for (int tn = 0; tn < 8; ++tn) {
            f32x4 c = {0.f, 0.f, 0.f, 0.f};
            short8 b = sW2[tn*64 + lane];
            c = __builtin_amdgcn_mfma_f32_16x16x32_bf16(afrag, b, c, 0, 0, 0);
            int col = (tn&3)*16 + m;
            if (tn < 4) {
                if (col < H) {
                    float bias = b_PP[col];
                    #pragma unroll
                    for (int reg = 0; reg < 4; ++reg)
                        sX[row0 + q*4 + reg][H + col] = f2bf1(fmaxf(c[reg] + bias, 0.f));
                }
            } else {
                float bias = (col < H) ? b_PA[col] : 0.f;
                #pragma unroll
                for (int reg = 0; reg < 4; ++reg)
                    pa[tn-4][reg] = fmaxf(c[reg] + bias, 0.f);
            }
        }
    }

    // ---- wave-level 16-row segment-sum of PA (seg sorted) ----
    #pragma unroll
    for (int tn4 = 0; tn4 < 4; ++tn4) {
        float v[16];
        #pragma unroll
        for (int g = 0; g < 4; ++g) {
            int src = m + (g << 4);
            #pragma unroll
            for (int r4 = 0; r4 < 4; ++r4)
                v[g*4 + r4] = __shfl(pa[tn4][r4], src, 64);
        }
        int col = tn4*16 + m;
        if (q == 0 && col < H) {
            float acc = v[0]; int cur = sg[0];
            #pragma unroll
            for (int r = 1; r < 16; ++r) {
                if (sg[r] != cur) {
                    atomicAdd(&PAsum[(size_t)cur*H + col], acc);
                    acc = 0.f; cur = sg[r];
                }
                acc += v[r];
            }
            atomicAdd(&PAsum[(size_t)cur*H + col], acc);
        }
    }

    // all wave-local LDS writes must land before fragment reads (wave-sync)
    asm volatile("s_waitcnt lgkmcnt(0)" ::: "memory");
    __builtin_amdgcn_sched_barrier(0);

    // ---- P = relu(X @ W_P + b_P), per-wave M=16 N=64 K=128; B from LDS ----
    {
        short8 afr[4];
        #pragma unroll
        for (int tk = 0; tk < 4; ++tk)
            afr[tk] = *(const short8*)&sX[row0 + m][tk*32 + q*8];
        f32x4 acc[4];
        #pragma unroll
        for (int tn = 0; tn < 4; ++tn) acc[tn] = (f32x4){0.f, 0.f, 0.f, 0.f};
        #pragma unroll
        for (int tk = 0; tk < 4; ++tk) {
            #pragma unroll
            for (int tn = 0; tn < 4; ++tn) {
                short8 b = sWP[(tk*4 + tn)*64 + lane];
                acc[tn] = __builtin_amdgcn_mfma_f32_16x16x32_bf16(afr[tk], b, acc[tn], 0, 0, 0);
            }
        }
        #pragma unroll
        for (int tn = 0; tn < 4; ++tn) {
            int col = tn*16 + m;
            if (col < H) {
                float bp = b_P[col];
                #pragma unroll
                for (int reg = 0; reg < 4; ++reg) {
                    int row = row0 + q*4 + reg;
                    Pout[(size_t)(p0 + row)*H + col] = fmaxf(acc[tn][reg] + bp, 0.f);
                }
            }
        }
    }
}

// ---------------------------------------------------------------------------
// K3: A = relu([AAb | PAsum] @ W_A + b_A), 64 atoms/block.
// ---------------------------------------------------------------------------
__global__ __launch_bounds__(256) void k_A(
    const ushort* __restrict__ AAb, const float* __restrict__ PAsum,
    const ushort* __restrict__ WAf, const float* __restrict__ b_A,
    float* __restrict__ Aout)
{
    __shared__ __align__(16) ushort sX[64][136];
    const int t = threadIdx.x, lane = t & 63, w = t >> 6;
    const int a0 = blockIdx.x * 64;
    const int row0 = w * 16;

    for (int idx = t; idx < 64*50; idx += 256) {
        int r = idx / 50, c = idx % 50;
        int rg = a0 + r;
        ushort aa = 0; float ps = 0.f;
        if (rg < NA) { aa = AAb[(size_t)rg*H + c]; ps = PAsum[(size_t)rg*H + c]; }
        sX[r][c] = aa;
        sX[r][H + c] = f2bf1(ps);
    }
    for (int idx = t; idx < 64*28; idx += 256) {
        int r = idx / 28, c = 100 + idx % 28;
        sX[r][c] = 0;
    }
    __syncthreads();

    short8 afr[4];
    #pragma unroll
    for (int tk = 0; tk < 4; ++tk)
        afr[tk] = *(const short8*)&sX[row0 + (lane&15)][tk*32 + (lane>>4)*8];
    const short8* B = (const short8*)WAf;
    f32x4 acc[4];
    #pragma unroll
    for (int tn = 0; tn < 4; ++tn) acc[tn] = (f32x4){0.f, 0.f, 0.f, 0.f};
    #pragma unroll
    for (int tk = 0; tk < 4; ++tk) {
        #pragma unroll
        for (int tn = 0; tn < 4; ++tn) {
            short8 b = B[(tk*4 + tn)*64 + lane];
            acc[tn] = __builtin_amdgcn_mfma_f32_16x16x32_bf16(afr[tk], b, acc[tn], 0, 0, 0);
        }
    }
    #pragma unroll
    for (int tn = 0; tn < 4; ++tn) {
        int col = tn*16 + (lane&15);
        if (col < H) {
            float ba = b_A[col];
            #pragma unroll
            for (int reg = 0; reg < 4; ++reg) {
                int row = row0 + (lane>>4)*4 + reg;
                int rg = a0 + row;
                if (rg < NA) Aout[(size_t)rg*H + col] = fmaxf(acc[tn][reg] + ba, 0.f);
            }
        }
    }
}

// ---------------------------------------------------------------------------
extern "C" void kernel_launch(void* const* d_in, const int* in_sizes, int n_in,
                              void* d_out, int out_size, void* d_ws, size_t ws_size,
                              hipStream_t stream)
{
    const float* af   = (const float*)d_in[0];
    const float* pf   = (const float*)d_in[1];
    const int*   seg  = (const int*)d_in[2];
    const int*   a2p  = (const int*)d_in[3];
    const float* W_AA = (const float*)d_in[4];
    const float* b_AA = (const float*)d_in[5];
    const float* W_PA = (const float*)d_in[6];
    const float* b_PA = (const float*)d_in[7];
    const float* W_A  = (const float*)d_in[8];
    const float* b_A  = (const float*)d_in[9];
    const float* W_AP = (const float*)d_in[10];
    const float* b_AP = (const float*)d_in[11];
    const float* W_PP = (const float*)d_in[12];
    const float* b_PP = (const float*)d_in[13];
    const float* W_P  = (const float*)d_in[14];
    const float* b_P  = (const float*)d_in[15];

    float* Aout = (float*)d_out;
    float* Pout = (float*)d_out + (size_t)NA * H;

    ushort*   AAb   = (ushort*)d_ws;                         // 5 MB
    float*    PAsum = (float*)(AAb + (size_t)NA * H);        // 10 MB
    ushort*   UV8   = (ushort*)(PAsum + (size_t)NA * H);     // 6.4 MB
    ushort*   WPf   = UV8 + (size_t)NA * 64;                 // 16 KB
    ushort*   WAf   = WPf + 4*4*64*8;                        // 16 KB
    ushort*   W2f   = WAf + 4*4*64*8;                        // 8 KB
    ushort*   WPREf = W2f + 8*64*8;                          // 36 KB

    hipMemsetAsync(PAsum, 0, (size_t)NA * H * sizeof(float), stream);
    k_prep_frags<<<16, 256, 0, stream>>>(W_P, W_A, W_PP, W_PA, W_AA, W_AP,
                                         WPf, WAf, W2f, WPREf);
    k_atom_pre<<<(NA + 63) / 64, 256, 0, stream>>>(af, WPREf, b_AA, AAb, UV8);
    k_pairs<<<NP / 64, 256, 0, stream>>>(pf, seg, a2p, UV8, b_PP, b_PA, b_AP, b_P,
                                         WPf, W2f, PAsum, Pout);
    k_A<<<(NA + 63) / 64, 256, 0, stream>>>(AAb, PAsum, WAf, b_A, Aout);
}